// Round 15
// baseline (419.706 us; speedup 1.0000x reference)
//
#include <hip/hip_runtime.h>

#define CDIM  3072
#define MROWS 8192
#define NOUT  9216
#define NTI   48     // K groups of 64

typedef __bf16 bf16x8 __attribute__((ext_vector_type(8)));
typedef float f32x4 __attribute__((ext_vector_type(4)));
typedef int i32x4 __attribute__((ext_vector_type(4)));

__device__ __forceinline__ unsigned short f2bf(float f) {
  union { float f; unsigned int u; } v; v.f = f;
  unsigned int u = v.u;
  return (unsigned short)((u + 0x7fffu + ((u >> 16) & 1u)) >> 16);  // RNE
}
__device__ __forceinline__ float bfu_lo(unsigned int u) {
  union { unsigned int v; float f; } x; x.v = u << 16; return x.f;
}
__device__ __forceinline__ float bfu_hi(unsigned int u) {
  union { unsigned int v; float f; } x; x.v = u & 0xffff0000u; return x.f;
}
__device__ __forceinline__ void gld16(const void* g, void* l) {
  __builtin_amdgcn_global_load_lds(
      (const __attribute__((address_space(1))) void*)g,
      (__attribute__((address_space(3))) void*)l, 16, 0, 0);
}

#define BARRIER() asm volatile("s_barrier" ::: "memory")

template<int N> __device__ __forceinline__ void vmw() {
  if constexpr (N == 4)      asm volatile("s_waitcnt vmcnt(4)" ::: "memory");
  else if constexpr (N == 0) asm volatile("s_waitcnt vmcnt(0)" ::: "memory");
}

// Requant helper: q packed int8x4 (exact reference int4 levels), f = 16*s/S.
// r = rint(q*f) in [-128,112] -> packed int8x4.
__device__ __forceinline__ unsigned int requant4(unsigned int u, float f) {
  const int q0 = (int)(signed char)(u & 0xff);
  const int q1 = (int)(signed char)((u >> 8) & 0xff);
  const int q2 = (int)(signed char)((u >> 16) & 0xff);
  const int q3 = (int)(signed char)(u >> 24);
  const int r0 = (int)rintf((float)q0 * f);
  const int r1 = (int)rintf((float)q1 * f);
  const int r2 = (int)rintf((float)q2 * f);
  const int r3 = (int)rintf((float)q3 * f);
  return (r0 & 0xff) | ((r1 & 0xff) << 8) | ((r2 & 0xff) << 16)
       | ((unsigned int)(r3 & 0xff) << 24);
}

// ---------------- K1: fused prep.
// blocks [0,9216): weight int4-quant + row requant -> Bq int8, Sb_r, Blor
// blocks [9216,11264): activation quant + row requant + lora -> Aq, Sa_r, Alor
__global__ __launch_bounds__(256) void k_prep(
    const float* __restrict__ wt, const float* __restrict__ pu,
    const float* __restrict__ x, const float* __restrict__ smooth,
    const float* __restrict__ pd,
    signed char* __restrict__ Bq, float* __restrict__ Sb_r,
    unsigned short* __restrict__ Blor,
    signed char* __restrict__ Aq, float* __restrict__ Sa_r,
    unsigned short* __restrict__ Alor) {
  __shared__ unsigned short xsb[4][3072];   // 24 KB (activation branch)
  __shared__ float plds[4][32][33];         // 16.5 KB
  __shared__ float sred[4];
  const int tid = threadIdx.x;

  if (blockIdx.x < NOUT) {
    // ---- weight row: pass 1 = group quant (exact reference q), pass 2 = requant
    const int row = blockIdx.x;
    unsigned int u[3]; float sl[3];
    #pragma unroll
    for (int it = 0; it < 3; ++it) {
      const int c = it * 1024 + tid * 4;
      const float4 v = *(const float4*)&wt[(size_t)row * CDIM + c];
      float am = fmaxf(fmaxf(fabsf(v.x), fabsf(v.y)), fmaxf(fabsf(v.z), fabsf(v.w)));
      #pragma unroll
      for (int off = 1; off < 16; off <<= 1) am = fmaxf(am, __shfl_xor(am, off));
      const float s = fmaxf(am / 7.0f, 1e-8f);                 // IEEE div (ref-exact)
      union { signed char c[4]; unsigned int u; } pk;
      pk.c[0] = (signed char)(int)fminf(fmaxf(rintf(v.x / s), -8.f), 7.f);
      pk.c[1] = (signed char)(int)fminf(fmaxf(rintf(v.y / s), -8.f), 7.f);
      pk.c[2] = (signed char)(int)fminf(fmaxf(rintf(v.z / s), -8.f), 7.f);
      pk.c[3] = (signed char)(int)fminf(fmaxf(rintf(v.w / s), -8.f), 7.f);
      u[it] = pk.u; sl[it] = s;
    }
    float smax = fmaxf(fmaxf(sl[0], sl[1]), sl[2]);
    #pragma unroll
    for (int off = 16; off < 64; off <<= 1) smax = fmaxf(smax, __shfl_xor(smax, off));
    if ((tid & 63) == 0) sred[tid >> 6] = smax;
    __syncthreads();
    const float S = fmaxf(fmaxf(sred[0], sred[1]), fmaxf(sred[2], sred[3]));
    const float inv16 = 16.0f / S;
    #pragma unroll
    for (int it = 0; it < 3; ++it) {
      const int c = it * 1024 + tid * 4;
      *(unsigned int*)&Bq[(size_t)row * CDIM + c] = requant4(u[it], sl[it] * inv16);
    }
    if (tid == 0) Sb_r[row] = S * 0.0625f;   // S/16
    if (tid < 32) Blor[row * 32 + tid] = f2bf(pu[row * 32 + tid]);
    return;
  }

  // ---- activation: 4 rows/block, wave per row
  const int blk = blockIdx.x - NOUT;
  const int w = tid >> 6, l = tid & 63;
  const int row = blk * 4 + w;
  const float* xr = x + (size_t)row * CDIM;
  unsigned int u[12]; float sl[12];

  #pragma unroll
  for (int it = 0; it < 12; ++it) {
    const int c = it * 256 + l * 4;
    const float4 xv = *(const float4*)&xr[c];
    const float4 sm = *(const float4*)&smooth[c];
    float4 xs;
    xs.x = xv.x / sm.x; xs.y = xv.y / sm.y;   // exact IEEE div
    xs.z = xv.z / sm.z; xs.w = xv.w / sm.w;
    ushort4 xb;
    xb.x = f2bf(xs.x); xb.y = f2bf(xs.y); xb.z = f2bf(xs.z); xb.w = f2bf(xs.w);
    *(ushort4*)&xsb[w][c] = xb;
    float am = fmaxf(fmaxf(fabsf(xs.x), fabsf(xs.y)), fmaxf(fabsf(xs.z), fabsf(xs.w)));
    #pragma unroll
    for (int off = 1; off < 16; off <<= 1) am = fmaxf(am, __shfl_xor(am, off));
    const float s = fmaxf(am / 7.0f, 1e-8f);
    union { signed char c[4]; unsigned int u; } pk;
    pk.c[0] = (signed char)(int)fminf(fmaxf(rintf(xs.x / s), -8.f), 7.f);
    pk.c[1] = (signed char)(int)fminf(fmaxf(rintf(xs.y / s), -8.f), 7.f);
    pk.c[2] = (signed char)(int)fminf(fmaxf(rintf(xs.z / s), -8.f), 7.f);
    pk.c[3] = (signed char)(int)fminf(fmaxf(rintf(xs.w / s), -8.f), 7.f);
    u[it] = pk.u; sl[it] = s;
  }
  float smax = sl[0];
  #pragma unroll
  for (int it = 1; it < 12; ++it) smax = fmaxf(smax, sl[it]);
  #pragma unroll
  for (int off = 16; off < 64; off <<= 1) smax = fmaxf(smax, __shfl_xor(smax, off));
  const float S = smax;
  const float inv16 = 16.0f / S;
  #pragma unroll
  for (int it = 0; it < 12; ++it) {
    const int c = it * 256 + l * 4;
    *(unsigned int*)&Aq[(size_t)row * CDIM + c] = requant4(u[it], sl[it] * inv16);
  }
  if (l == 0) Sa_r[row] = S * 0.0625f;     // S/16
  __syncthreads();

  // lora: lora_act = xs(bf16) @ pd, pd L2-hot per block
  const int ch = tid >> 3, rg = tid & 7;
  float acc[4][4] = {};
  for (int i = 0; i < 48; ++i) {
    const int c = ch * 2 + i * 64;
    const float4 p0 = *(const float4*)&pd[(size_t)c * 32 + rg * 4];
    const float4 p1 = *(const float4*)&pd[(size_t)(c + 1) * 32 + rg * 4];
    #pragma unroll
    for (int r4 = 0; r4 < 4; ++r4) {
      const unsigned int uu = *(const unsigned int*)&xsb[r4][c];
      const float xa = bfu_lo(uu), xb = bfu_hi(uu);
      acc[r4][0] += xa * p0.x + xb * p1.x;
      acc[r4][1] += xa * p0.y + xb * p1.y;
      acc[r4][2] += xa * p0.z + xb * p1.z;
      acc[r4][3] += xa * p0.w + xb * p1.w;
    }
  }
  #pragma unroll
  for (int r4 = 0; r4 < 4; ++r4)
    #pragma unroll
    for (int jj = 0; jj < 4; ++jj)
      plds[r4][rg * 4 + jj][ch] = acc[r4][jj];
  __syncthreads();
  if (tid < 128) {
    const int rr = tid >> 5, r = tid & 31;
    float ssum = 0.f;
    #pragma unroll
    for (int cc = 0; cc < 32; ++cc) ssum += plds[rr][r][cc];
    Alor[(size_t)(blk * 4 + rr) * 32 + r] = f2bf(ssum);
  }
}

// ---------------- K3: pure int8 128x128 GEMM, i32 accumulation over all K,
// 4 waves, 64x64/wave, r7 skeleton (runtime-parity dbuf, race-verified).
// LDS buf (16384 B): A[128][64]i8 @0, B @8192. 4 loads/thread/group
// {A,A,B,B}; vmcnt(4) = 1-group distance. Swizzle chunk ^= (row>>1)&3
// (measured 0-conflict). ZERO VALU in K-loop: mfma C-in chains into AGPRs.
// launch_bounds (256,3): 3 blocks/CU (LDS 96KB/160KB). Register ledger:
// 68 arch VGPR + 64 pure-AGPR acc = 132 <= 170 budget at 3 waves/EU — the
// acc is never VALU-touched in the loop (unlike r9's spill case).
__global__ __launch_bounds__(256, 3) void k_gemmi8(
    const signed char* __restrict__ Aq, const signed char* __restrict__ Bq,
    const float* __restrict__ Sa_r, const float* __restrict__ Sb_r,
    const unsigned short* __restrict__ Alor, const unsigned short* __restrict__ Blor,
    const float* __restrict__ bias,
    const float* __restrict__ nqw, const float* __restrict__ nkw,
    const float* __restrict__ fcos, const float* __restrict__ fsin,
    float* __restrict__ outp) {
  __shared__ char lds[32768];
  const int tid = threadIdx.x;
  const int w = tid >> 6, l = tid & 63;
  const int wm = w >> 1, wn = w & 1;          // 2x2 waves, 64x64 each
  const int l16 = l & 15, g16 = l >> 4;
  // XCD swizzle: xcd owns by-band [8*xcd,8*xcd+8), swept in 4-by x 9-bx chunks
  const int xcd = blockIdx.x & 7;
  const int j = blockIdx.x >> 3;              // 0..575
  const int chunk = j / 36;                   // 0..15
  const int t = j - chunk * 36;               // 0..35
  const int by = xcd * 8 + (chunk & 1) * 4 + t / 9;
  const int bx = (chunk >> 1) * 9 + t % 9;
  const int m0 = by * 128, n0 = bx * 128;
  const int fsb = (g16 ^ ((l16 >> 1) & 3)) << 4;
  const int rl = tid >> 2;
  const int swz = (((tid & 3) ^ ((rl >> 1) & 3)) << 4);
  const signed char* As0 = Aq + (size_t)(m0 + rl) * CDIM + swz;
  const signed char* As1 = As0 + (size_t)64 * CDIM;
  const signed char* Bs0 = Bq + (size_t)(n0 + rl) * CDIM + swz;
  const signed char* Bs1 = Bs0 + (size_t)64 * CDIM;

  i32x4 acc[4][4] = {};

  // prologue: stage group 0 into buf0
  gld16(As0, lds + tid * 16);            gld16(As1, lds + 4096 + tid * 16);
  gld16(Bs0, lds + 8192 + tid * 16);     gld16(Bs1, lds + 8192 + 4096 + tid * 16);

  #pragma unroll 1
  for (int g = 0; g < NTI; ++g) {
    const int cb = (g & 1) * 16384;           // current buf
    const int nb = ((g + 1) & 1) * 16384;     // next buf
    if (g < NTI - 1) {
      const size_t kc = (size_t)(g + 1) * 64;
      gld16(As0 + kc, lds + nb + tid * 16);
      gld16(As1 + kc, lds + nb + 4096 + tid * 16);
      gld16(Bs0 + kc, lds + nb + 8192 + tid * 16);
      gld16(Bs1 + kc, lds + nb + 8192 + 4096 + tid * 16);
      vmw<4>();
    } else {
      vmw<0>();
    }
    BARRIER();
    i32x4 av[4], bv[4];
    #pragma unroll
    for (int mi = 0; mi < 4; ++mi)
      av[mi] = *(const i32x4*)(lds + cb + (wm * 64 + mi * 16 + l16) * 64 + fsb);
    #pragma unroll
    for (int ni = 0; ni < 4; ++ni)
      bv[ni] = *(const i32x4*)(lds + cb + 8192 + (wn * 64 + ni * 16 + l16) * 64 + fsb);
    __builtin_amdgcn_s_setprio(1);
    #pragma unroll
    for (int mi = 0; mi < 4; ++mi)
      #pragma unroll
      for (int ni = 0; ni < 4; ++ni)
        acc[mi][ni] = __builtin_amdgcn_mfma_i32_16x16x64_i8(av[mi], bv[ni], acc[mi][ni], 0, 0, 0);
    __builtin_amdgcn_s_setprio(0);
    BARRIER();
  }

  // ---- stage lora into buf0 (WAR-safe: after final loop barrier)
  {
    const char* Al0 = (const char*)Alor + (size_t)(m0 + rl) * 64 + swz;
    const char* Bl0 = (const char*)Blor + (size_t)(n0 + rl) * 64 + swz;
    gld16(Al0, lds + tid * 16);            gld16(Al0 + 4096, lds + 4096 + tid * 16);
    gld16(Bl0, lds + 8192 + tid * 16);     gld16(Bl0 + 4096, lds + 8192 + 4096 + tid * 16);
  }

  // ---- convert acc -> f32 with row/col scales (overlaps lora-load latency)
  f32x4 facc[4][4];
  float sbv[4];
  #pragma unroll
  for (int ni = 0; ni < 4; ++ni) sbv[ni] = Sb_r[n0 + wn * 64 + ni * 16 + l16];
  #pragma unroll
  for (int mi = 0; mi < 4; ++mi) {
    const f32x4 sa4 = *(const f32x4*)&Sa_r[m0 + wm * 64 + mi * 16 + g16 * 4];
    #pragma unroll
    for (int ni = 0; ni < 4; ++ni) {
      const f32x4 sab = sa4 * sbv[ni];
      facc[mi][ni] = __builtin_convertvector(acc[mi][ni], f32x4) * sab;
    }
  }

  // ---- lora bf16 pass from buf0
  vmw<0>();
  BARRIER();
  {
    bf16x8 bl[4];
    #pragma unroll
    for (int ni = 0; ni < 4; ++ni)
      bl[ni] = *(const bf16x8*)(lds + 8192 + (wn * 64 + ni * 16 + l16) * 64 + fsb);
    #pragma unroll
    for (int mi = 0; mi < 4; ++mi) {
      const bf16x8 al = *(const bf16x8*)(lds + (wm * 64 + mi * 16 + l16) * 64 + fsb);
      #pragma unroll
      for (int ni = 0; ni < 4; ++ni)
        facc[mi][ni] = __builtin_amdgcn_mfma_f32_16x16x32_bf16(al, bl[ni], facc[mi][ni], 0, 0, 0);
    }
  }

  // ---------------- fused epilogue (bias -> RMSNorm+RoPE for q/k) ----------------
  float bvv[4];
  #pragma unroll
  for (int ni = 0; ni < 4; ++ni) bvv[ni] = bias[n0 + wn * 64 + ni * 16 + l16];
  #pragma unroll
  for (int mi = 0; mi < 4; ++mi)
    #pragma unroll
    for (int ni = 0; ni < 4; ++ni)
      #pragma unroll
      for (int jj = 0; jj < 4; ++jj) facc[mi][ni][jj] += bvv[ni];

  if (n0 < 6144) {
    const float* nwt = (n0 < 3072) ? nqw : nkw;
    float nw[4];
    #pragma unroll
    for (int ni = 0; ni < 4; ++ni) nw[ni] = nwt[wn * 64 + ni * 16 + l16];

    float part[4][4];
    #pragma unroll
    for (int mi = 0; mi < 4; ++mi)
      #pragma unroll
      for (int jj = 0; jj < 4; ++jj) {
        float ssum = 0.f;
        #pragma unroll
        for (int ni = 0; ni < 4; ++ni) ssum += facc[mi][ni][jj] * facc[mi][ni][jj];
        #pragma unroll
        for (int off = 1; off < 16; off <<= 1) ssum += __shfl_xor(ssum, off);
        part[mi][jj] = ssum;   // partial over this wave's 64 cols (row fixed)
      }

    __syncthreads();
    float* sq = (float*)lds;   // [128 rows][2 col-waves]
    if (l16 == 0) {
      #pragma unroll
      for (int mi = 0; mi < 4; ++mi)
        #pragma unroll
        for (int jj = 0; jj < 4; ++jj)
          sq[(wm * 64 + mi * 16 + g16 * 4 + jj) * 2 + wn] = part[mi][jj];
    }
    __syncthreads();

    #pragma unroll
    for (int mi = 0; mi < 4; ++mi) {
      #pragma unroll
      for (int jj = 0; jj < 4; ++jj) {
        const int r128 = wm * 64 + mi * 16 + g16 * 4 + jj;
        const float other = sq[r128 * 2 + (wn ^ 1)];
        const float rinv = 1.0f / sqrtf((part[mi][jj] + other) * (1.0f / 128.0f) + 1e-6f);
        const int row = m0 + r128;
        const int sidx = row & 4095;
        #pragma unroll
        for (int ni = 0; ni < 4; ++ni) {
          const int p = wn * 32 + ni * 8 + (l16 >> 1);
          const float cv = fcos[(size_t)sidx * 64 + p];
          const float sv = fsin[(size_t)sidx * 64 + p];
          const float v = facc[mi][ni][jj] * rinv * nw[ni];
          const float o = __shfl_xor(v, 1);
          const float res = ((l & 1) == 0) ? (v * cv - o * sv) : (o * sv + v * cv);
          __builtin_nontemporal_store(res, &outp[(size_t)row * NOUT + n0 + wn * 64 + ni * 16 + l16]);
        }
      }
    }
  } else {
    #pragma unroll
    for (int ni = 0; ni < 4; ++ni) {
      const int gn = n0 + wn * 64 + ni * 16 + l16;
      #pragma unroll
      for (int mi = 0; mi < 4; ++mi) {
        const int gm = m0 + wm * 64 + mi * 16 + g16 * 4;
        #pragma unroll
        for (int jj = 0; jj < 4; ++jj)
          __builtin_nontemporal_store(facc[mi][ni][jj], &outp[(size_t)(gm + jj) * NOUT + gn]);
      }
    }
  }
}

extern "C" void kernel_launch(void* const* d_in, const int* in_sizes, int n_in,
                              void* d_out, int out_size, void* d_ws, size_t ws_size,
                              hipStream_t stream) {
  const float* x      = (const float*)d_in[0];
  const float* smooth = (const float*)d_in[1];
  const float* weight = (const float*)d_in[2];
  const float* pd     = (const float*)d_in[3];
  const float* pu     = (const float*)d_in[4];
  const float* bias   = (const float*)d_in[5];
  const float* nqw    = (const float*)d_in[6];
  const float* nkw    = (const float*)d_in[7];
  const float* fcos   = (const float*)d_in[8];
  const float* fsin   = (const float*)d_in[9];
  float* out = (float*)d_out;

  char* ws = (char*)d_ws;
  signed char* Aq   = (signed char*)ws;                       // 25,165,824
  signed char* Bq   = (signed char*)(ws + 25165824);          // 28,311,552
  float* Sa_r       = (float*)(ws + 53477376);                //    32,768
  float* Sb_r       = (float*)(ws + 53510144);                //    36,864
  unsigned short* Alor = (unsigned short*)(ws + 53547008);    //   524,288
  unsigned short* Blor = (unsigned short*)(ws + 54071296);    //   589,824

  k_prep<<<dim3(NOUT + MROWS / 4), dim3(256), 0, stream>>>(
      weight, pu, x, smooth, pd, Bq, Sb_r, Blor, Aq, Sa_r, Alor);
  k_gemmi8<<<dim3(4608), dim3(256), 0, stream>>>(Aq, Bq, Sa_r, Sb_r, Alor, Blor,
                                                 bias, nqw, nkw, fcos, fsin, out);
}

// Round 16
// 413.704 us; speedup vs baseline: 1.0145x; 1.0145x over previous
//
#include <hip/hip_runtime.h>

#define CDIM  3072
#define MROWS 8192
#define NOUT  9216
#define NTI   48     // K groups of 64

typedef __bf16 bf16x8 __attribute__((ext_vector_type(8)));
typedef float f32x4 __attribute__((ext_vector_type(4)));
typedef int i32x4 __attribute__((ext_vector_type(4)));

__device__ __forceinline__ unsigned short f2bf(float f) {
  union { float f; unsigned int u; } v; v.f = f;
  unsigned int u = v.u;
  return (unsigned short)((u + 0x7fffu + ((u >> 16) & 1u)) >> 16);  // RNE
}
__device__ __forceinline__ float bfu_lo(unsigned int u) {
  union { unsigned int v; float f; } x; x.v = u << 16; return x.f;
}
__device__ __forceinline__ float bfu_hi(unsigned int u) {
  union { unsigned int v; float f; } x; x.v = u & 0xffff0000u; return x.f;
}
__device__ __forceinline__ void gld16(const void* g, void* l) {
  __builtin_amdgcn_global_load_lds(
      (const __attribute__((address_space(1))) void*)g,
      (__attribute__((address_space(3))) void*)l, 16, 0, 0);
}

#define BARRIER() asm volatile("s_barrier" ::: "memory")

template<int N> __device__ __forceinline__ void vmw() {
  if constexpr (N == 4)      asm volatile("s_waitcnt vmcnt(4)" ::: "memory");
  else if constexpr (N == 0) asm volatile("s_waitcnt vmcnt(0)" ::: "memory");
}

// Requant helper: q packed int8x4 (exact reference int4 levels), f = 16*s/S.
// r = rint(q*f) in [-128,112] -> packed int8x4.
__device__ __forceinline__ unsigned int requant4(unsigned int u, float f) {
  const int q0 = (int)(signed char)(u & 0xff);
  const int q1 = (int)(signed char)((u >> 8) & 0xff);
  const int q2 = (int)(signed char)((u >> 16) & 0xff);
  const int q3 = (int)(signed char)(u >> 24);
  const int r0 = (int)rintf((float)q0 * f);
  const int r1 = (int)rintf((float)q1 * f);
  const int r2 = (int)rintf((float)q2 * f);
  const int r3 = (int)rintf((float)q3 * f);
  return (r0 & 0xff) | ((r1 & 0xff) << 8) | ((r2 & 0xff) << 16)
       | ((unsigned int)(r3 & 0xff) << 24);
}

// ---------------- K1: fused prep.
// blocks [0,9216): weight int4-quant + row requant -> Bq int8, Sb_r, Blor
// blocks [9216,11264): activation quant + row requant + lora -> Aq, Sa_r, Alor
__global__ __launch_bounds__(256) void k_prep(
    const float* __restrict__ wt, const float* __restrict__ pu,
    const float* __restrict__ x, const float* __restrict__ smooth,
    const float* __restrict__ pd,
    signed char* __restrict__ Bq, float* __restrict__ Sb_r,
    unsigned short* __restrict__ Blor,
    signed char* __restrict__ Aq, float* __restrict__ Sa_r,
    unsigned short* __restrict__ Alor) {
  __shared__ unsigned short xsb[4][3072];   // 24 KB (activation branch)
  __shared__ float plds[4][32][33];         // 16.5 KB
  __shared__ float sred[4];
  const int tid = threadIdx.x;

  if (blockIdx.x < NOUT) {
    // ---- weight row: pass 1 = group quant (exact reference q), pass 2 = requant
    const int row = blockIdx.x;
    unsigned int u[3]; float sl[3];
    #pragma unroll
    for (int it = 0; it < 3; ++it) {
      const int c = it * 1024 + tid * 4;
      const float4 v = *(const float4*)&wt[(size_t)row * CDIM + c];
      float am = fmaxf(fmaxf(fabsf(v.x), fabsf(v.y)), fmaxf(fabsf(v.z), fabsf(v.w)));
      #pragma unroll
      for (int off = 1; off < 16; off <<= 1) am = fmaxf(am, __shfl_xor(am, off));
      const float s = fmaxf(am / 7.0f, 1e-8f);                 // IEEE div (ref-exact)
      union { signed char c[4]; unsigned int u; } pk;
      pk.c[0] = (signed char)(int)fminf(fmaxf(rintf(v.x / s), -8.f), 7.f);
      pk.c[1] = (signed char)(int)fminf(fmaxf(rintf(v.y / s), -8.f), 7.f);
      pk.c[2] = (signed char)(int)fminf(fmaxf(rintf(v.z / s), -8.f), 7.f);
      pk.c[3] = (signed char)(int)fminf(fmaxf(rintf(v.w / s), -8.f), 7.f);
      u[it] = pk.u; sl[it] = s;
    }
    float smax = fmaxf(fmaxf(sl[0], sl[1]), sl[2]);
    #pragma unroll
    for (int off = 16; off < 64; off <<= 1) smax = fmaxf(smax, __shfl_xor(smax, off));
    if ((tid & 63) == 0) sred[tid >> 6] = smax;
    __syncthreads();
    const float S = fmaxf(fmaxf(sred[0], sred[1]), fmaxf(sred[2], sred[3]));
    const float inv16 = 16.0f / S;
    #pragma unroll
    for (int it = 0; it < 3; ++it) {
      const int c = it * 1024 + tid * 4;
      *(unsigned int*)&Bq[(size_t)row * CDIM + c] = requant4(u[it], sl[it] * inv16);
    }
    if (tid == 0) Sb_r[row] = S * 0.0625f;   // S/16
    if (tid < 32) Blor[row * 32 + tid] = f2bf(pu[row * 32 + tid]);
    return;
  }

  // ---- activation: 4 rows/block, wave per row
  const int blk = blockIdx.x - NOUT;
  const int w = tid >> 6, l = tid & 63;
  const int row = blk * 4 + w;
  const float* xr = x + (size_t)row * CDIM;
  unsigned int u[12]; float sl[12];

  #pragma unroll
  for (int it = 0; it < 12; ++it) {
    const int c = it * 256 + l * 4;
    const float4 xv = *(const float4*)&xr[c];
    const float4 sm = *(const float4*)&smooth[c];
    float4 xs;
    xs.x = xv.x / sm.x; xs.y = xv.y / sm.y;   // exact IEEE div
    xs.z = xv.z / sm.z; xs.w = xv.w / sm.w;
    ushort4 xb;
    xb.x = f2bf(xs.x); xb.y = f2bf(xs.y); xb.z = f2bf(xs.z); xb.w = f2bf(xs.w);
    *(ushort4*)&xsb[w][c] = xb;
    float am = fmaxf(fmaxf(fabsf(xs.x), fabsf(xs.y)), fmaxf(fabsf(xs.z), fabsf(xs.w)));
    #pragma unroll
    for (int off = 1; off < 16; off <<= 1) am = fmaxf(am, __shfl_xor(am, off));
    const float s = fmaxf(am / 7.0f, 1e-8f);
    union { signed char c[4]; unsigned int u; } pk;
    pk.c[0] = (signed char)(int)fminf(fmaxf(rintf(xs.x / s), -8.f), 7.f);
    pk.c[1] = (signed char)(int)fminf(fmaxf(rintf(xs.y / s), -8.f), 7.f);
    pk.c[2] = (signed char)(int)fminf(fmaxf(rintf(xs.z / s), -8.f), 7.f);
    pk.c[3] = (signed char)(int)fminf(fmaxf(rintf(xs.w / s), -8.f), 7.f);
    u[it] = pk.u; sl[it] = s;
  }
  float smax = sl[0];
  #pragma unroll
  for (int it = 1; it < 12; ++it) smax = fmaxf(smax, sl[it]);
  #pragma unroll
  for (int off = 16; off < 64; off <<= 1) smax = fmaxf(smax, __shfl_xor(smax, off));
  const float S = smax;
  const float inv16 = 16.0f / S;
  #pragma unroll
  for (int it = 0; it < 12; ++it) {
    const int c = it * 256 + l * 4;
    *(unsigned int*)&Aq[(size_t)row * CDIM + c] = requant4(u[it], sl[it] * inv16);
  }
  if (l == 0) Sa_r[row] = S * 0.0625f;     // S/16
  __syncthreads();

  // lora: lora_act = xs(bf16) @ pd, pd L2-hot per block
  const int ch = tid >> 3, rg = tid & 7;
  float acc[4][4] = {};
  for (int i = 0; i < 48; ++i) {
    const int c = ch * 2 + i * 64;
    const float4 p0 = *(const float4*)&pd[(size_t)c * 32 + rg * 4];
    const float4 p1 = *(const float4*)&pd[(size_t)(c + 1) * 32 + rg * 4];
    #pragma unroll
    for (int r4 = 0; r4 < 4; ++r4) {
      const unsigned int uu = *(const unsigned int*)&xsb[r4][c];
      const float xa = bfu_lo(uu), xb = bfu_hi(uu);
      acc[r4][0] += xa * p0.x + xb * p1.x;
      acc[r4][1] += xa * p0.y + xb * p1.y;
      acc[r4][2] += xa * p0.z + xb * p1.z;
      acc[r4][3] += xa * p0.w + xb * p1.w;
    }
  }
  #pragma unroll
  for (int r4 = 0; r4 < 4; ++r4)
    #pragma unroll
    for (int jj = 0; jj < 4; ++jj)
      plds[r4][rg * 4 + jj][ch] = acc[r4][jj];
  __syncthreads();
  if (tid < 128) {
    const int rr = tid >> 5, r = tid & 31;
    float ssum = 0.f;
    #pragma unroll
    for (int cc = 0; cc < 32; ++cc) ssum += plds[rr][r][cc];
    Alor[(size_t)(blk * 4 + rr) * 32 + r] = f2bf(ssum);
  }
}

// ---------------- K3: pure int8 128x128 GEMM, i32 acc over all K, 4 waves.
// RING-3 deep prefetch (slot = g%3, 16 KB each: A[128][64] @0, B @8192).
// Section g: vmw<4> -> BARRIER -> stage(g+2) -> compute(g).
//   RAW: stage g issued at section g-2 (~2 group-times ~1850cy >= HBM 900);
//        at sec g's vmw, outstanding = {g+1, g+2-prev} <= 8; vmcnt(4) retires
//        the oldest 4 = stage g (FIFO).
//   WAR: stage g+2 targets slot (g+2)%3 = (g-1)%3, last read by compute g-1;
//        every wave passes sec g's BARRIER only after finishing compute g-1,
//        and stage g+2 issues after that barrier. In-flight stages {g+1,g+2}
//        never touch slot g%3 being read.
// ONE barrier per group (was 2). Tail: sec 46 stages lora into slot 0 (last
// read by compute 45); sec 47 vmw<4>; epilogue vmw<0>.
// ZERO VALU in K-loop (mfma C-in chains in AGPRs; no dequant -> no r10 spill).
__global__ __launch_bounds__(256, 2) void k_gemmi8(
    const signed char* __restrict__ Aq, const signed char* __restrict__ Bq,
    const float* __restrict__ Sa_r, const float* __restrict__ Sb_r,
    const unsigned short* __restrict__ Alor, const unsigned short* __restrict__ Blor,
    const float* __restrict__ bias,
    const float* __restrict__ nqw, const float* __restrict__ nkw,
    const float* __restrict__ fcos, const float* __restrict__ fsin,
    float* __restrict__ outp) {
  __shared__ char lds[49152];   // 3 slots x 16384
  const int tid = threadIdx.x;
  const int w = tid >> 6, l = tid & 63;
  const int wm = w >> 1, wn = w & 1;          // 2x2 waves, 64x64 each
  const int l16 = l & 15, g16 = l >> 4;
  // XCD swizzle: xcd owns by-band [8*xcd,8*xcd+8), swept in 4-by x 9-bx chunks
  const int xcd = blockIdx.x & 7;
  const int j = blockIdx.x >> 3;              // 0..575
  const int chunk = j / 36;                   // 0..15
  const int t = j - chunk * 36;               // 0..35
  const int by = xcd * 8 + (chunk & 1) * 4 + t / 9;
  const int bx = (chunk >> 1) * 9 + t % 9;
  const int m0 = by * 128, n0 = bx * 128;
  const int fsb = (g16 ^ ((l16 >> 1) & 3)) << 4;
  const int rl = tid >> 2;
  const int swz = (((tid & 3) ^ ((rl >> 1) & 3)) << 4);
  const signed char* As0 = Aq + (size_t)(m0 + rl) * CDIM + swz;
  const signed char* As1 = As0 + (size_t)64 * CDIM;
  const signed char* Bs0 = Bq + (size_t)(n0 + rl) * CDIM + swz;
  const signed char* Bs1 = Bs0 + (size_t)64 * CDIM;

  const int aoff = (wm * 64 + l16) * 64 + fsb;
  const int boff = 8192 + (wn * 64 + l16) * 64 + fsb;
  char* dA0 = lds + tid * 16;
  char* dA1 = lds + 4096 + tid * 16;
  char* dB0 = lds + 8192 + tid * 16;
  char* dB1 = lds + 12288 + tid * 16;

  i32x4 acc[4][4] = {};
  int koff = 0;

#define STAGE(OFF) do {                                             \
    gld16(As0 + koff, dA0 + (OFF)); gld16(As1 + koff, dA1 + (OFF)); \
    gld16(Bs0 + koff, dB0 + (OFF)); gld16(Bs1 + koff, dB1 + (OFF)); \
    koff += 64; } while (0)

#define STAGE_LORA(OFF) do {                                            \
    const char* Al0 = (const char*)Alor + (size_t)(m0 + rl) * 64 + swz; \
    const char* Bl0 = (const char*)Blor + (size_t)(n0 + rl) * 64 + swz; \
    gld16(Al0, dA0 + (OFF)); gld16(Al0 + 4096, dA1 + (OFF));            \
    gld16(Bl0, dB0 + (OFF)); gld16(Bl0 + 4096, dB1 + (OFF)); } while (0)

#define COMPUTE(OFF) do {                                                      \
    i32x4 av[4], bv[4];                                                        \
    _Pragma("unroll")                                                          \
    for (int mi = 0; mi < 4; ++mi)                                             \
      av[mi] = *(const i32x4*)(lds + (OFF) + aoff + mi * 1024);                \
    _Pragma("unroll")                                                          \
    for (int ni = 0; ni < 4; ++ni)                                             \
      bv[ni] = *(const i32x4*)(lds + (OFF) + boff + ni * 1024);                \
    __builtin_amdgcn_s_setprio(1);                                             \
    _Pragma("unroll")                                                          \
    for (int mi = 0; mi < 4; ++mi)                                             \
      _Pragma("unroll")                                                        \
      for (int ni = 0; ni < 4; ++ni)                                           \
        acc[mi][ni] = __builtin_amdgcn_mfma_i32_16x16x64_i8(av[mi], bv[ni],    \
                                                            acc[mi][ni], 0, 0, 0); \
    __builtin_amdgcn_s_setprio(0);                                             \
  } while (0)

  // prologue: stage g0 -> slot0, g1 -> slot1
  STAGE(0);
  STAGE(16384);

  #pragma unroll 1
  for (int i = 0; i < 16; ++i) {
    // sec 3i: compute slot0, stage 3i+2 -> slot2
    vmw<4>(); BARRIER();
    STAGE(32768);
    COMPUTE(0);
    // sec 3i+1: compute slot1, stage 3i+3 -> slot0 (i==15: lora -> slot0)
    vmw<4>(); BARRIER();
    if (i < 15) STAGE(0); else STAGE_LORA(0);
    COMPUTE(16384);
    // sec 3i+2: compute slot2, stage 3i+4 -> slot1 (i==15: none)
    vmw<4>(); BARRIER();
    if (i < 15) STAGE(16384);
    COMPUTE(32768);
  }
#undef STAGE
#undef STAGE_LORA
#undef COMPUTE

  // ---- convert acc -> f32 with row/col scales (overlaps lora-load latency)
  f32x4 facc[4][4];
  float sbv[4];
  #pragma unroll
  for (int ni = 0; ni < 4; ++ni) sbv[ni] = Sb_r[n0 + wn * 64 + ni * 16 + l16];
  #pragma unroll
  for (int mi = 0; mi < 4; ++mi) {
    const f32x4 sa4 = *(const f32x4*)&Sa_r[m0 + wm * 64 + mi * 16 + g16 * 4];
    #pragma unroll
    for (int ni = 0; ni < 4; ++ni) {
      const f32x4 sab = sa4 * sbv[ni];
      facc[mi][ni] = __builtin_convertvector(acc[mi][ni], f32x4) * sab;
    }
  }

  // ---- lora bf16 pass from slot0
  vmw<0>();
  BARRIER();
  {
    bf16x8 bl[4];
    #pragma unroll
    for (int ni = 0; ni < 4; ++ni)
      bl[ni] = *(const bf16x8*)(lds + 8192 + (wn * 64 + ni * 16 + l16) * 64 + fsb);
    #pragma unroll
    for (int mi = 0; mi < 4; ++mi) {
      const bf16x8 al = *(const bf16x8*)(lds + (wm * 64 + mi * 16 + l16) * 64 + fsb);
      #pragma unroll
      for (int ni = 0; ni < 4; ++ni)
        facc[mi][ni] = __builtin_amdgcn_mfma_f32_16x16x32_bf16(al, bl[ni], facc[mi][ni], 0, 0, 0);
    }
  }

  // ---------------- fused epilogue (bias -> RMSNorm+RoPE for q/k) ----------------
  float bvv[4];
  #pragma unroll
  for (int ni = 0; ni < 4; ++ni) bvv[ni] = bias[n0 + wn * 64 + ni * 16 + l16];
  #pragma unroll
  for (int mi = 0; mi < 4; ++mi)
    #pragma unroll
    for (int ni = 0; ni < 4; ++ni)
      #pragma unroll
      for (int jj = 0; jj < 4; ++jj) facc[mi][ni][jj] += bvv[ni];

  if (n0 < 6144) {
    const float* nwt = (n0 < 3072) ? nqw : nkw;
    float nw[4];
    #pragma unroll
    for (int ni = 0; ni < 4; ++ni) nw[ni] = nwt[wn * 64 + ni * 16 + l16];

    float part[4][4];
    #pragma unroll
    for (int mi = 0; mi < 4; ++mi)
      #pragma unroll
      for (int jj = 0; jj < 4; ++jj) {
        float ssum = 0.f;
        #pragma unroll
        for (int ni = 0; ni < 4; ++ni) ssum += facc[mi][ni][jj] * facc[mi][ni][jj];
        #pragma unroll
        for (int off = 1; off < 16; off <<= 1) ssum += __shfl_xor(ssum, off);
        part[mi][jj] = ssum;   // partial over this wave's 64 cols (row fixed)
      }

    __syncthreads();
    float* sq = (float*)lds;   // [128 rows][2 col-waves]
    if (l16 == 0) {
      #pragma unroll
      for (int mi = 0; mi < 4; ++mi)
        #pragma unroll
        for (int jj = 0; jj < 4; ++jj)
          sq[(wm * 64 + mi * 16 + g16 * 4 + jj) * 2 + wn] = part[mi][jj];
    }
    __syncthreads();

    #pragma unroll
    for (int mi = 0; mi < 4; ++mi) {
      #pragma unroll
      for (int jj = 0; jj < 4; ++jj) {
        const int r128 = wm * 64 + mi * 16 + g16 * 4 + jj;
        const float other = sq[r128 * 2 + (wn ^ 1)];
        const float rinv = 1.0f / sqrtf((part[mi][jj] + other) * (1.0f / 128.0f) + 1e-6f);
        const int row = m0 + r128;
        const int sidx = row & 4095;
        #pragma unroll
        for (int ni = 0; ni < 4; ++ni) {
          const int p = wn * 32 + ni * 8 + (l16 >> 1);
          const float cv = fcos[(size_t)sidx * 64 + p];
          const float sv = fsin[(size_t)sidx * 64 + p];
          const float v = facc[mi][ni][jj] * rinv * nw[ni];
          const float o = __shfl_xor(v, 1);
          const float res = ((l & 1) == 0) ? (v * cv - o * sv) : (o * sv + v * cv);
          __builtin_nontemporal_store(res, &outp[(size_t)row * NOUT + n0 + wn * 64 + ni * 16 + l16]);
        }
      }
    }
  } else {
    #pragma unroll
    for (int ni = 0; ni < 4; ++ni) {
      const int gn = n0 + wn * 64 + ni * 16 + l16;
      #pragma unroll
      for (int mi = 0; mi < 4; ++mi) {
        const int gm = m0 + wm * 64 + mi * 16 + g16 * 4;
        #pragma unroll
        for (int jj = 0; jj < 4; ++jj)
          __builtin_nontemporal_store(facc[mi][ni][jj], &outp[(size_t)(gm + jj) * NOUT + gn]);
      }
    }
  }
}

extern "C" void kernel_launch(void* const* d_in, const int* in_sizes, int n_in,
                              void* d_out, int out_size, void* d_ws, size_t ws_size,
                              hipStream_t stream) {
  const float* x      = (const float*)d_in[0];
  const float* smooth = (const float*)d_in[1];
  const float* weight = (const float*)d_in[2];
  const float* pd     = (const float*)d_in[3];
  const float* pu     = (const float*)d_in[4];
  const float* bias   = (const float*)d_in[5];
  const float* nqw    = (const float*)d_in[6];
  const float* nkw    = (const float*)d_in[7];
  const float* fcos   = (const float*)d_in[8];
  const float* fsin   = (const float*)d_in[9];
  float* out = (float*)d_out;

  char* ws = (char*)d_ws;
  signed char* Aq   = (signed char*)ws;                       // 25,165,824
  signed char* Bq   = (signed char*)(ws + 25165824);          // 28,311,552
  float* Sa_r       = (float*)(ws + 53477376);                //    32,768
  float* Sb_r       = (float*)(ws + 53510144);                //    36,864
  unsigned short* Alor = (unsigned short*)(ws + 53547008);    //   524,288
  unsigned short* Blor = (unsigned short*)(ws + 54071296);    //   589,824

  k_prep<<<dim3(NOUT + MROWS / 4), dim3(256), 0, stream>>>(
      weight, pu, x, smooth, pd, Bq, Sb_r, Blor, Aq, Sa_r, Alor);
  k_gemmi8<<<dim3(4608), dim3(256), 0, stream>>>(Aq, Bq, Sa_r, Sb_r, Alor, Blor,
                                                 bias, nqw, nkw, fcos, fsin, out);
}

// Round 17
// 369.244 us; speedup vs baseline: 1.1367x; 1.1204x over previous
//
#include <hip/hip_runtime.h>

#define CDIM  3072
#define MROWS 8192
#define NOUT  9216
#define NW    24     // K windows of 128 bytes (2 x K=64 MFMA slabs)

typedef __bf16 bf16x8 __attribute__((ext_vector_type(8)));
typedef float f32x4 __attribute__((ext_vector_type(4)));
typedef int i32x4 __attribute__((ext_vector_type(4)));

__device__ __forceinline__ unsigned short f2bf(float f) {
  union { float f; unsigned int u; } v; v.f = f;
  unsigned int u = v.u;
  return (unsigned short)((u + 0x7fffu + ((u >> 16) & 1u)) >> 16);  // RNE
}
__device__ __forceinline__ float bfu_lo(unsigned int u) {
  union { unsigned int v; float f; } x; x.v = u << 16; return x.f;
}
__device__ __forceinline__ float bfu_hi(unsigned int u) {
  union { unsigned int v; float f; } x; x.v = u & 0xffff0000u; return x.f;
}
__device__ __forceinline__ void gld16(const void* g, void* l) {
  __builtin_amdgcn_global_load_lds(
      (const __attribute__((address_space(1))) void*)g,
      (__attribute__((address_space(3))) void*)l, 16, 0, 0);
}

#define BARRIER() asm volatile("s_barrier" ::: "memory")
#define LGKM0()   asm volatile("s_waitcnt lgkmcnt(0)" ::: "memory")

template<int N> __device__ __forceinline__ void vmw() {
  if constexpr (N == 8)      asm volatile("s_waitcnt vmcnt(8)" ::: "memory");
  else if constexpr (N == 4) asm volatile("s_waitcnt vmcnt(4)" ::: "memory");
  else if constexpr (N == 0) asm volatile("s_waitcnt vmcnt(0)" ::: "memory");
  // N==63: no wait
}

// Requant helper: q packed int8x4 (exact reference int4 levels), f = 16*s/S.
__device__ __forceinline__ unsigned int requant4(unsigned int u, float f) {
  const int q0 = (int)(signed char)(u & 0xff);
  const int q1 = (int)(signed char)((u >> 8) & 0xff);
  const int q2 = (int)(signed char)((u >> 16) & 0xff);
  const int q3 = (int)(signed char)(u >> 24);
  const int r0 = (int)rintf((float)q0 * f);
  const int r1 = (int)rintf((float)q1 * f);
  const int r2 = (int)rintf((float)q2 * f);
  const int r3 = (int)rintf((float)q3 * f);
  return (r0 & 0xff) | ((r1 & 0xff) << 8) | ((r2 & 0xff) << 16)
       | ((unsigned int)(r3 & 0xff) << 24);
}

// ---------------- K1: fused prep (unchanged from r14).
__global__ __launch_bounds__(256) void k_prep(
    const float* __restrict__ wt, const float* __restrict__ pu,
    const float* __restrict__ x, const float* __restrict__ smooth,
    const float* __restrict__ pd,
    signed char* __restrict__ Bq, float* __restrict__ Sb_r,
    unsigned short* __restrict__ Blor,
    signed char* __restrict__ Aq, float* __restrict__ Sa_r,
    unsigned short* __restrict__ Alor) {
  __shared__ unsigned short xsb[4][3072];
  __shared__ float plds[4][32][33];
  __shared__ float sred[4];
  const int tid = threadIdx.x;

  if (blockIdx.x < NOUT) {
    const int row = blockIdx.x;
    unsigned int u[3]; float sl[3];
    #pragma unroll
    for (int it = 0; it < 3; ++it) {
      const int c = it * 1024 + tid * 4;
      const float4 v = *(const float4*)&wt[(size_t)row * CDIM + c];
      float am = fmaxf(fmaxf(fabsf(v.x), fabsf(v.y)), fmaxf(fabsf(v.z), fabsf(v.w)));
      #pragma unroll
      for (int off = 1; off < 16; off <<= 1) am = fmaxf(am, __shfl_xor(am, off));
      const float s = fmaxf(am / 7.0f, 1e-8f);                 // IEEE div (ref-exact)
      union { signed char c[4]; unsigned int u; } pk;
      pk.c[0] = (signed char)(int)fminf(fmaxf(rintf(v.x / s), -8.f), 7.f);
      pk.c[1] = (signed char)(int)fminf(fmaxf(rintf(v.y / s), -8.f), 7.f);
      pk.c[2] = (signed char)(int)fminf(fmaxf(rintf(v.z / s), -8.f), 7.f);
      pk.c[3] = (signed char)(int)fminf(fmaxf(rintf(v.w / s), -8.f), 7.f);
      u[it] = pk.u; sl[it] = s;
    }
    float smax = fmaxf(fmaxf(sl[0], sl[1]), sl[2]);
    #pragma unroll
    for (int off = 16; off < 64; off <<= 1) smax = fmaxf(smax, __shfl_xor(smax, off));
    if ((tid & 63) == 0) sred[tid >> 6] = smax;
    __syncthreads();
    const float S = fmaxf(fmaxf(sred[0], sred[1]), fmaxf(sred[2], sred[3]));
    const float inv16 = 16.0f / S;
    #pragma unroll
    for (int it = 0; it < 3; ++it) {
      const int c = it * 1024 + tid * 4;
      *(unsigned int*)&Bq[(size_t)row * CDIM + c] = requant4(u[it], sl[it] * inv16);
    }
    if (tid == 0) Sb_r[row] = S * 0.0625f;   // S/16
    if (tid < 32) Blor[row * 32 + tid] = f2bf(pu[row * 32 + tid]);
    return;
  }

  const int blk = blockIdx.x - NOUT;
  const int w = tid >> 6, l = tid & 63;
  const int row = blk * 4 + w;
  const float* xr = x + (size_t)row * CDIM;
  unsigned int u[12]; float sl[12];

  #pragma unroll
  for (int it = 0; it < 12; ++it) {
    const int c = it * 256 + l * 4;
    const float4 xv = *(const float4*)&xr[c];
    const float4 sm = *(const float4*)&smooth[c];
    float4 xs;
    xs.x = xv.x / sm.x; xs.y = xv.y / sm.y;   // exact IEEE div
    xs.z = xv.z / sm.z; xs.w = xv.w / sm.w;
    ushort4 xb;
    xb.x = f2bf(xs.x); xb.y = f2bf(xs.y); xb.z = f2bf(xs.z); xb.w = f2bf(xs.w);
    *(ushort4*)&xsb[w][c] = xb;
    float am = fmaxf(fmaxf(fabsf(xs.x), fabsf(xs.y)), fmaxf(fabsf(xs.z), fabsf(xs.w)));
    #pragma unroll
    for (int off = 1; off < 16; off <<= 1) am = fmaxf(am, __shfl_xor(am, off));
    const float s = fmaxf(am / 7.0f, 1e-8f);
    union { signed char c[4]; unsigned int u; } pk;
    pk.c[0] = (signed char)(int)fminf(fmaxf(rintf(xs.x / s), -8.f), 7.f);
    pk.c[1] = (signed char)(int)fminf(fmaxf(rintf(xs.y / s), -8.f), 7.f);
    pk.c[2] = (signed char)(int)fminf(fmaxf(rintf(xs.z / s), -8.f), 7.f);
    pk.c[3] = (signed char)(int)fminf(fmaxf(rintf(xs.w / s), -8.f), 7.f);
    u[it] = pk.u; sl[it] = s;
  }
  float smax = sl[0];
  #pragma unroll
  for (int it = 1; it < 12; ++it) smax = fmaxf(smax, sl[it]);
  #pragma unroll
  for (int off = 16; off < 64; off <<= 1) smax = fmaxf(smax, __shfl_xor(smax, off));
  const float S = smax;
  const float inv16 = 16.0f / S;
  #pragma unroll
  for (int it = 0; it < 12; ++it) {
    const int c = it * 256 + l * 4;
    *(unsigned int*)&Aq[(size_t)row * CDIM + c] = requant4(u[it], sl[it] * inv16);
  }
  if (l == 0) Sa_r[row] = S * 0.0625f;     // S/16
  __syncthreads();

  const int ch = tid >> 3, rg = tid & 7;
  float acc[4][4] = {};
  for (int i = 0; i < 48; ++i) {
    const int c = ch * 2 + i * 64;
    const float4 p0 = *(const float4*)&pd[(size_t)c * 32 + rg * 4];
    const float4 p1 = *(const float4*)&pd[(size_t)(c + 1) * 32 + rg * 4];
    #pragma unroll
    for (int r4 = 0; r4 < 4; ++r4) {
      const unsigned int uu = *(const unsigned int*)&xsb[r4][c];
      const float xa = bfu_lo(uu), xb = bfu_hi(uu);
      acc[r4][0] += xa * p0.x + xb * p1.x;
      acc[r4][1] += xa * p0.y + xb * p1.y;
      acc[r4][2] += xa * p0.z + xb * p1.z;
      acc[r4][3] += xa * p0.w + xb * p1.w;
    }
  }
  #pragma unroll
  for (int r4 = 0; r4 < 4; ++r4)
    #pragma unroll
    for (int jj = 0; jj < 4; ++jj)
      plds[r4][rg * 4 + jj][ch] = acc[r4][jj];
  __syncthreads();
  if (tid < 128) {
    const int rr = tid >> 5, r = tid & 31;
    float ssum = 0.f;
    #pragma unroll
    for (int cc = 0; cc < 32; ++cc) ssum += plds[rr][r][cc];
    Alor[(size_t)(blk * 4 + rr) * 32 + r] = f2bf(ssum);
  }
}

// ---------------- K3: i8 256x256-tile GEMM, 4-phase windows (r5 skeleton).
// 512 thr, 8 waves (2M x 4N, 128x64/wave). Window = BK 128 bytes, kk halves
// of 64 (one mfma_i32_16x16x64_i8 K-slab each). LDS regions 16 KB (BYTES):
// A(kk,par) = (kk*2+par)*16384; B at +65536. Swizzle chunk ^= (row>>1)&3.
// Per phase: frag ds_reads + 2 gld16 stage -> BARRIER -> LGKM0 -> 16 MFMA
// (setprio) -> BARRIER. vmcnt(8) end-ph1/ph3 (12 in flight -> retire oldest 4,
// 1.5-window distance). Ledger identical to r5 (race-screened r4/r5).
template<int VM1, int VM3, int DO01, int DO23>
__device__ __forceinline__ void gemm_window(
    char* lds, i32x4 (&acc)[8][4],
    const signed char* Asrc, const signed char* Bsrc,
    int tid, int arow, int brow, int fsb, int par, int t) {
  const int A0 = par * 16384;
  const int A1 = 32768 + par * 16384;
  const int B0 = 65536 + par * 16384;
  const int B1 = 98304 + par * 16384;
  const int A1n = 32768 + (par ^ 1) * 16384;
  const int B1n = 98304 + (par ^ 1) * 16384;
  i32x4 a[4], b[4];

  // ---- phase 0: kk0, mi 0-3 (+ stage A-kk1 of window t+1)
  #pragma unroll
  for (int ni = 0; ni < 4; ++ni) b[ni] = *(const i32x4*)(lds + B0 + (brow + ni * 16) * 64 + fsb);
  #pragma unroll
  for (int mi = 0; mi < 4; ++mi) a[mi] = *(const i32x4*)(lds + A0 + (arow + mi * 16) * 64 + fsb);
  if (DO01) {
    const int kc = (t + 1) * 128 + 64;
    gld16(Asrc + kc, lds + A1n + tid * 16);
    gld16(Asrc + (size_t)128 * CDIM + kc, lds + A1n + 8192 + tid * 16);
  }
  BARRIER(); LGKM0();
  __builtin_amdgcn_s_setprio(1);
  #pragma unroll
  for (int mi = 0; mi < 4; ++mi)
    #pragma unroll
    for (int ni = 0; ni < 4; ++ni)
      acc[mi][ni] = __builtin_amdgcn_mfma_i32_16x16x64_i8(a[mi], b[ni], acc[mi][ni], 0, 0, 0);
  __builtin_amdgcn_s_setprio(0);
  BARRIER();

  // ---- phase 1: kk0, mi 4-7 (+ stage B-kk1 of window t+1; VM1)
  #pragma unroll
  for (int mi = 0; mi < 4; ++mi) a[mi] = *(const i32x4*)(lds + A0 + (arow + 64 + mi * 16) * 64 + fsb);
  if (DO01) {
    const int kc = (t + 1) * 128 + 64;
    gld16(Bsrc + kc, lds + B1n + tid * 16);
    gld16(Bsrc + (size_t)128 * CDIM + kc, lds + B1n + 8192 + tid * 16);
  }
  BARRIER(); LGKM0();
  __builtin_amdgcn_s_setprio(1);
  #pragma unroll
  for (int mi = 0; mi < 4; ++mi)
    #pragma unroll
    for (int ni = 0; ni < 4; ++ni)
      acc[4 + mi][ni] = __builtin_amdgcn_mfma_i32_16x16x64_i8(a[mi], b[ni], acc[4 + mi][ni], 0, 0, 0);
  __builtin_amdgcn_s_setprio(0);
  vmw<VM1>();
  BARRIER();

  // ---- phase 2: kk1, mi 0-3 (+ stage A-kk0 of window t+2 into A0)
  #pragma unroll
  for (int ni = 0; ni < 4; ++ni) b[ni] = *(const i32x4*)(lds + B1 + (brow + ni * 16) * 64 + fsb);
  #pragma unroll
  for (int mi = 0; mi < 4; ++mi) a[mi] = *(const i32x4*)(lds + A1 + (arow + mi * 16) * 64 + fsb);
  if (DO23) {
    const int kc = (t + 2) * 128;
    gld16(Asrc + kc, lds + A0 + tid * 16);
    gld16(Asrc + (size_t)128 * CDIM + kc, lds + A0 + 8192 + tid * 16);
  }
  BARRIER(); LGKM0();
  __builtin_amdgcn_s_setprio(1);
  #pragma unroll
  for (int mi = 0; mi < 4; ++mi)
    #pragma unroll
    for (int ni = 0; ni < 4; ++ni)
      acc[mi][ni] = __builtin_amdgcn_mfma_i32_16x16x64_i8(a[mi], b[ni], acc[mi][ni], 0, 0, 0);
  __builtin_amdgcn_s_setprio(0);
  BARRIER();

  // ---- phase 3: kk1, mi 4-7 (+ stage B-kk0 of window t+2; VM3)
  #pragma unroll
  for (int mi = 0; mi < 4; ++mi) a[mi] = *(const i32x4*)(lds + A1 + (arow + 64 + mi * 16) * 64 + fsb);
  if (DO23) {
    const int kc = (t + 2) * 128;
    gld16(Bsrc + kc, lds + B0 + tid * 16);
    gld16(Bsrc + (size_t)128 * CDIM + kc, lds + B0 + 8192 + tid * 16);
  }
  BARRIER(); LGKM0();
  __builtin_amdgcn_s_setprio(1);
  #pragma unroll
  for (int mi = 0; mi < 4; ++mi)
    #pragma unroll
    for (int ni = 0; ni < 4; ++ni)
      acc[4 + mi][ni] = __builtin_amdgcn_mfma_i32_16x16x64_i8(a[mi], b[ni], acc[4 + mi][ni], 0, 0, 0);
  __builtin_amdgcn_s_setprio(0);
  vmw<VM3>();
  BARRIER();
}

__global__ __launch_bounds__(512, 2) void k_gemmi8(
    const signed char* __restrict__ Aq, const signed char* __restrict__ Bq,
    const float* __restrict__ Sa_r, const float* __restrict__ Sb_r,
    const unsigned short* __restrict__ Alor, const unsigned short* __restrict__ Blor,
    const float* __restrict__ bias,
    const float* __restrict__ nqw, const float* __restrict__ nkw,
    const float* __restrict__ fcos, const float* __restrict__ fsin,
    float* __restrict__ outp) {
  __shared__ char lds[131072];  // 128 KiB: 8 regions x 16 KB
  const int tid = threadIdx.x;
  const int w = tid >> 6, l = tid & 63;
  const int wr = w >> 2, wc = w & 3;               // 2M x 4N waves, 128x64 each
  const int l16 = l & 15, g16 = l >> 4;
  // 2D-chunked XCD swizzle (r5): xcd owns by-band [4*xcd,4*xcd+4)
  const int xcd = blockIdx.x & 7;
  const int jj = blockIdx.x >> 3;      // 0..143
  const int chunk = jj / 36;           // 0..3
  const int tt = jj - chunk * 36;      // 0..35
  const int by = xcd * 4 + tt / 9;
  const int bx = chunk * 9 + tt % 9;
  const int n0 = bx * 256, m0 = by * 256;
  const int arow = wr * 128 + l16;
  const int brow = wc * 64 + l16;
  const int fsb = (g16 ^ ((l16 >> 1) & 3)) << 4;       // frag chunk swizzle
  const int sr = tid >> 2;                             // staging row 0..127
  const int ss = (((tid & 3) ^ ((sr >> 1) & 3)) << 4); // pre-swizzled source chunk
  const signed char* Asrc = Aq + (size_t)(m0 + sr) * CDIM + ss;
  const signed char* Bsrc = Bq + (size_t)(n0 + sr) * CDIM + ss;
  i32x4 acc[8][4] = {};

  // prologue: stage kk0(0), kk1(0), kk0(1); retire kk0(0)
  gld16(Asrc, lds + tid * 16);                  gld16(Asrc + (size_t)128 * CDIM, lds + 8192 + tid * 16);
  gld16(Bsrc, lds + 65536 + tid * 16);          gld16(Bsrc + (size_t)128 * CDIM, lds + 73728 + tid * 16);
  gld16(Asrc + 64, lds + 32768 + tid * 16);     gld16(Asrc + (size_t)128 * CDIM + 64, lds + 40960 + tid * 16);
  gld16(Bsrc + 64, lds + 98304 + tid * 16);     gld16(Bsrc + (size_t)128 * CDIM + 64, lds + 106496 + tid * 16);
  gld16(Asrc + 128, lds + 16384 + tid * 16);    gld16(Asrc + (size_t)128 * CDIM + 128, lds + 24576 + tid * 16);
  gld16(Bsrc + 128, lds + 81920 + tid * 16);    gld16(Bsrc + (size_t)128 * CDIM + 128, lds + 90112 + tid * 16);
  vmw<8>(); BARRIER();

  #pragma unroll 1
  for (int t = 0; t <= NW - 3; ++t)
    gemm_window<8, 8, 1, 1>(lds, acc, Asrc, Bsrc, tid, arow, brow, fsb, t & 1, t);
  gemm_window<8, 4, 1, 0>(lds, acc, Asrc, Bsrc, tid, arow, brow, fsb, (NW - 2) & 1, NW - 2);
  gemm_window<0, 63, 0, 0>(lds, acc, Asrc, Bsrc, tid, arow, brow, fsb, (NW - 1) & 1, NW - 1);

  // ---- stage lora tiles (A -> region 0, B -> region @65536); WAR-safe after
  // the final window's last barrier.
  {
    const char* Al0 = (const char*)Alor + (size_t)(m0 + sr) * 64 + ss;
    const char* Bl0 = (const char*)Blor + (size_t)(n0 + sr) * 64 + ss;
    gld16(Al0, lds + tid * 16);            gld16(Al0 + 128 * 64, lds + 8192 + tid * 16);
    gld16(Bl0, lds + 65536 + tid * 16);    gld16(Bl0 + 128 * 64, lds + 73728 + tid * 16);
  }

  // ---- convert acc -> f32 with row/col scales (overlaps lora-load latency)
  f32x4 facc[8][4];
  float sbv[4];
  #pragma unroll
  for (int ni = 0; ni < 4; ++ni) sbv[ni] = Sb_r[n0 + wc * 64 + ni * 16 + l16];
  #pragma unroll
  for (int q = 0; q < 8; ++q) {
    const f32x4 sa4 = *(const f32x4*)&Sa_r[m0 + wr * 128 + q * 16 + g16 * 4];
    #pragma unroll
    for (int ni = 0; ni < 4; ++ni)
      facc[q][ni] = __builtin_convertvector(acc[q][ni], f32x4) * (sa4 * sbv[ni]);
  }

  // ---- lora bf16 pass (K=32)
  vmw<0>(); BARRIER();
  {
    bf16x8 bl[4];
    #pragma unroll
    for (int ni = 0; ni < 4; ++ni)
      bl[ni] = *(const bf16x8*)(lds + 65536 + (brow + ni * 16) * 64 + fsb);
    #pragma unroll
    for (int q = 0; q < 8; ++q) {
      const bf16x8 al = *(const bf16x8*)(lds + (arow + q * 16) * 64 + fsb);
      #pragma unroll
      for (int ni = 0; ni < 4; ++ni)
        facc[q][ni] = __builtin_amdgcn_mfma_f32_16x16x32_bf16(al, bl[ni], facc[q][ni], 0, 0, 0);
    }
  }

  // ---------------- fused epilogue (bias -> RMSNorm+RoPE for q/k) — r5 port
  float bvv[4];
  #pragma unroll
  for (int ni = 0; ni < 4; ++ni) bvv[ni] = bias[n0 + wc * 64 + ni * 16 + l16];
  #pragma unroll
  for (int q = 0; q < 8; ++q)
    #pragma unroll
    for (int ni = 0; ni < 4; ++ni)
      #pragma unroll
      for (int j = 0; j < 4; ++j) facc[q][ni][j] += bvv[ni];

  if (n0 < 6144) {
    const float* nwt = (n0 < 3072) ? nqw : nkw;
    float nw[4];
    #pragma unroll
    for (int ni = 0; ni < 4; ++ni) nw[ni] = nwt[(wc & 1) * 64 + ni * 16 + l16];

    float part[8][4];
    #pragma unroll
    for (int q = 0; q < 8; ++q)
      #pragma unroll
      for (int j = 0; j < 4; ++j) {
        float ssum = 0.f;
        #pragma unroll
        for (int ni = 0; ni < 4; ++ni) ssum += facc[q][ni][j] * facc[q][ni][j];
        #pragma unroll
        for (int off = 1; off < 16; off <<= 1) ssum += __shfl_xor(ssum, off);
        part[q][j] = ssum;   // per-row partial over this wave's 64 cols
      }

    __syncthreads();                    // LDS regions done; reuse as sq
    float* sq = (float*)lds;            // [2][128][2][2]
    if (l16 == 0) {
      #pragma unroll
      for (int q = 0; q < 8; ++q)
        #pragma unroll
        for (int j = 0; j < 4; ++j) {
          const int r128 = q * 16 + g16 * 4 + j;
          sq[(((wr * 128 + r128) * 2 + (wc >> 1)) * 2) + (wc & 1)] = part[q][j];
        }
    }
    __syncthreads();

    #pragma unroll
    for (int q = 0; q < 8; ++q) {
      #pragma unroll
      for (int j = 0; j < 4; ++j) {
        const int r128 = q * 16 + g16 * 4 + j;
        const float other = sq[(((wr * 128 + r128) * 2 + (wc >> 1)) * 2) + ((wc & 1) ^ 1)];
        const float rinv = 1.0f / sqrtf((part[q][j] + other) * (1.0f / 128.0f) + 1e-6f);
        const int row = m0 + wr * 128 + r128;
        const int sidx = row & 4095;
        #pragma unroll
        for (int ni = 0; ni < 4; ++ni) {
          const int p = (wc & 1) * 32 + ni * 8 + (l16 >> 1);
          const float cv = fcos[(size_t)sidx * 64 + p];
          const float sv = fsin[(size_t)sidx * 64 + p];
          const float v = facc[q][ni][j] * rinv * nw[ni];
          const float o = __shfl_xor(v, 1);
          const float res = ((l & 1) == 0) ? (v * cv - o * sv) : (o * sv + v * cv);
          __builtin_nontemporal_store(res, &outp[(size_t)row * NOUT + n0 + wc * 64 + ni * 16 + l16]);
        }
      }
    }
  } else {
    #pragma unroll
    for (int ni = 0; ni < 4; ++ni) {
      const int gn = n0 + wc * 64 + ni * 16 + l16;
      #pragma unroll
      for (int q = 0; q < 8; ++q) {
        const int gm = m0 + wr * 128 + q * 16 + g16 * 4;
        #pragma unroll
        for (int j = 0; j < 4; ++j)
          __builtin_nontemporal_store(facc[q][ni][j], &outp[(size_t)(gm + j) * NOUT + gn]);
      }
    }
  }
}

extern "C" void kernel_launch(void* const* d_in, const int* in_sizes, int n_in,
                              void* d_out, int out_size, void* d_ws, size_t ws_size,
                              hipStream_t stream) {
  const float* x      = (const float*)d_in[0];
  const float* smooth = (const float*)d_in[1];
  const float* weight = (const float*)d_in[2];
  const float* pd     = (const float*)d_in[3];
  const float* pu     = (const float*)d_in[4];
  const float* bias   = (const float*)d_in[5];
  const float* nqw    = (const float*)d_in[6];
  const float* nkw    = (const float*)d_in[7];
  const float* fcos   = (const float*)d_in[8];
  const float* fsin   = (const float*)d_in[9];
  float* out = (float*)d_out;

  char* ws = (char*)d_ws;
  signed char* Aq   = (signed char*)ws;                       // 25,165,824
  signed char* Bq   = (signed char*)(ws + 25165824);          // 28,311,552
  float* Sa_r       = (float*)(ws + 53477376);                //    32,768
  float* Sb_r       = (float*)(ws + 53510144);                //    36,864
  unsigned short* Alor = (unsigned short*)(ws + 53547008);    //   524,288
  unsigned short* Blor = (unsigned short*)(ws + 54071296);    //   589,824

  k_prep<<<dim3(NOUT + MROWS / 4), dim3(256), 0, stream>>>(
      weight, pu, x, smooth, pd, Bq, Sb_r, Blor, Aq, Sa_r, Alor);
  k_gemmi8<<<dim3(1152), dim3(512), 0, stream>>>(Aq, Bq, Sa_r, Sb_r, Alor, Blor,
                                                 bias, nqw, nkw, fcos, fsin, out);
}